// Round 4
// baseline (329.905 us; speedup 1.0000x reference)
//
#include <hip/hip_runtime.h>

// SelfAttention: out = softmax((xWq)(xWk)^T/32) @ (xWv), f32, S=4096, D=1024.
// Q,K and QK^T in fp16 hi/lo split (3-MFMA); V path single MFMA.
// R3b: QK^T is a 3-buffer deep-pipelined kernel (counted vmcnt(6), raw
// s_barrier, swizzled LDS, 32x32x16 MFMA, setprio, XCD swizzle).
// ws layout (MiB): Qh 0, Ql 8, Kh 16, Kl 24, Vt 32, S 40..104 (f32)
//   P 0..32 (reuses dead Q/K); temps in dead S region: xh 40, xl 48, Wt* 56..68

typedef _Float16 f16;
typedef f16 f16x8 __attribute__((ext_vector_type(8)));
typedef f16 f16x4v __attribute__((ext_vector_type(4)));
typedef float f32x4 __attribute__((ext_vector_type(4)));
typedef float f32x16 __attribute__((ext_vector_type(16)));
typedef unsigned short u16;
typedef u16 u16x8 __attribute__((ext_vector_type(8)));

extern __shared__ char dsm[];  // single dynamic-LDS symbol for the whole TU

__device__ __forceinline__ void split_f32(float v, f16& h, f16& l) {
  h = (f16)v;
  l = (f16)(v - (float)h);
}

__device__ __forceinline__ void gload16(const void* g, void* l) {
  __builtin_amdgcn_global_load_lds(
      (const __attribute__((address_space(1))) void*)g,
      (__attribute__((address_space(3))) void*)l, 16, 0, 0);
}

// ---- prep: split x -> xh, xl (f16) ----
__global__ __launch_bounds__(256) void k_xsplit(const float* __restrict__ x,
                                                f16* __restrict__ xh,
                                                f16* __restrict__ xl) {
  const size_t i = ((size_t)blockIdx.x * 256 + threadIdx.x) * 4;
  float4 f = *(const float4*)&x[i];
  f16x4v h, l;
  f16 hh, ll;
  split_f32(f.x, hh, ll); h[0] = hh; l[0] = ll;
  split_f32(f.y, hh, ll); h[1] = hh; l[1] = ll;
  split_f32(f.z, hh, ll); h[2] = hh; l[2] = ll;
  split_f32(f.w, hh, ll); h[3] = hh; l[3] = ll;
  *(f16x4v*)&xh[i] = h;
  *(f16x4v*)&xl[i] = l;
}

// ---- prep: transpose+split W [k][n] f32 -> Wt_h, Wt_l [n][k] f16 ----
__global__ __launch_bounds__(256) void k_wsplit(
    const float* __restrict__ Wq, const float* __restrict__ Wk,
    const float* __restrict__ Wv, f16* __restrict__ qh, f16* __restrict__ ql,
    f16* __restrict__ kh, f16* __restrict__ kl, f16* __restrict__ vh,
    f16* __restrict__ vl) {
  __shared__ float sh[64][65];
  const int z = blockIdx.z;
  const float* __restrict__ W = (z == 0) ? Wq : (z == 1) ? Wk : Wv;
  f16* __restrict__ oh = (z == 0) ? qh : (z == 1) ? kh : vh;
  f16* __restrict__ ol = (z == 0) ? ql : (z == 1) ? kl : vl;
  const int kb = blockIdx.x * 64, nb = blockIdx.y * 64;
  const int t = threadIdx.x;
  const int r = t >> 2, c4 = (t & 3) * 16;
#pragma unroll
  for (int i = 0; i < 4; ++i) {
    float4 f = *(const float4*)&W[(size_t)(kb + r) * 1024 + nb + c4 + i * 4];
    sh[r][c4 + i * 4 + 0] = f.x;
    sh[r][c4 + i * 4 + 1] = f.y;
    sh[r][c4 + i * 4 + 2] = f.z;
    sh[r][c4 + i * 4 + 3] = f.w;
  }
  __syncthreads();
  const int n = t >> 2, ks = (t & 3) * 16;
  u16x8 h0, h1, l0, l1;
#pragma unroll
  for (int i = 0; i < 8; ++i) {
    f16 h, l;
    split_f32(sh[ks + i][n], h, l);
    h0[i] = __builtin_bit_cast(u16, h);
    l0[i] = __builtin_bit_cast(u16, l);
    split_f32(sh[ks + 8 + i][n], h, l);
    h1[i] = __builtin_bit_cast(u16, h);
    l1[i] = __builtin_bit_cast(u16, l);
  }
  const size_t o = (size_t)(nb + n) * 1024 + kb + ks;
  *(u16x8*)&oh[o] = h0;
  *(u16x8*)&oh[o + 8] = h1;
  *(u16x8*)&ol[o] = l0;
  *(u16x8*)&ol[o + 8] = l1;
}

// ---- QK^T: S = (Q.K^T)/32, 3-buffer pipelined, 32x32x16, split 3-MFMA ----
// tile 256x128, BK=32, 512 thr (8 waves 4x2), LDS 3 x 48 KiB.
// buffer layout: Ah[0,16K) Bh[16K,24K) Al[24K,40K) Bl[40K,48K); rows of 64 B,
// swizzle: 16B-slot ^= (row>>1)&3 (applied on global src and ds_read addr).
__global__ __launch_bounds__(512, 1) void k_qkt(
    const f16* __restrict__ Qh, const f16* __restrict__ Ql,
    const f16* __restrict__ Kh, const f16* __restrict__ Kl,
    float* __restrict__ S) {
  char* smem = dsm;
  constexpr int K = 1024, N = 4096, TB = 49152, nT = K / 32;
  const int tid = threadIdx.x;
  const int lane = tid & 63, wv = tid >> 6;
  const int wm = wv >> 1, wn = wv & 1;
  const int bid = blockIdx.x;                    // 512 blocks
  const int wg = (bid & 7) * 64 + (bid >> 3);    // bijective XCD swizzle
  const int bx = wg >> 5, by = wg & 31;          // 16 x 32
  const int brow = bx * 256, bcol = by * 128;

  const int srow = lane >> 2;                              // staging row 0..15
  const int scol = 8 * ((lane & 3) ^ ((lane >> 3) & 3));   // inv-swizzled col

  const f16* gA[2] = {Qh, Ql};
  const f16* gB[2] = {Kh, Kl};

  auto stage = [&](int buf, int t) {
    const int kt = t * 32;
    char* bb = smem + TB * buf;
#pragma unroll
    for (int hl = 0; hl < 2; ++hl) {
      const f16* Ap = gA[hl] + (size_t)(brow + srow) * K + kt + scol;
      char* lA = bb + (hl ? 24576 : 0);
#pragma unroll
      for (int i = 0; i < 2; ++i) {
        const int g = wv * 2 + i;  // 16 row-groups of A
        gload16(Ap + (size_t)16 * g * K, lA + g * 1024);
      }
      const f16* Bp = gB[hl] + (size_t)(bcol + 16 * wv + srow) * K + kt + scol;
      gload16(Bp, bb + (hl ? 40960 : 16384) + wv * 1024);
    }
  };

  f32x16 acc[2][2] = {};
  const int rA0 = wm * 64 + (lane & 31);
  const int rB0 = wn * 64 + (lane & 31);
  const int ch0 = lane >> 5;

  stage(0, 0);
  stage(1, 1);
  for (int t = 0; t < nT; ++t) {
    if (t < nT - 1) {
      asm volatile("s_waitcnt vmcnt(6)" ::: "memory");  // G_t done; G_{t+1} in flight
    } else {
      asm volatile("s_waitcnt vmcnt(0)" ::: "memory");  // last tile: drain
    }
    __builtin_amdgcn_sched_barrier(0);
    __builtin_amdgcn_s_barrier();
    __builtin_amdgcn_sched_barrier(0);
    if (t + 2 < nT) stage((t + 2) % 3, t + 2);

    const char* bb = smem + TB * (t % 3);
    f16x8 ah[2][2], al[2][2], bh[2][2], bl[2][2];  // [ks][frag]
#pragma unroll
    for (int ks = 0; ks < 2; ++ks) {
      const int ch = 2 * ks + ch0;
#pragma unroll
      for (int f = 0; f < 2; ++f) {
        const int ra = rA0 + f * 32;
        const int oa = ra * 64 + ((ch ^ ((ra >> 1) & 3)) * 16);
        ah[ks][f] = *(const f16x8*)(bb + oa);
        al[ks][f] = *(const f16x8*)(bb + 24576 + oa);
        const int rb = rB0 + f * 32;
        const int ob = rb * 64 + ((ch ^ ((rb >> 1) & 3)) * 16);
        bh[ks][f] = *(const f16x8*)(bb + 16384 + ob);
        bl[ks][f] = *(const f16x8*)(bb + 40960 + ob);
      }
    }
    __builtin_amdgcn_s_setprio(1);
#pragma unroll
    for (int ks = 0; ks < 2; ++ks)
#pragma unroll
      for (int fm = 0; fm < 2; ++fm)
#pragma unroll
        for (int fn = 0; fn < 2; ++fn) {
          acc[fm][fn] = __builtin_amdgcn_mfma_f32_32x32x16_f16(
              ah[ks][fm], bh[ks][fn], acc[fm][fn], 0, 0, 0);
          acc[fm][fn] = __builtin_amdgcn_mfma_f32_32x32x16_f16(
              ah[ks][fm], bl[ks][fn], acc[fm][fn], 0, 0, 0);
          acc[fm][fn] = __builtin_amdgcn_mfma_f32_32x32x16_f16(
              al[ks][fm], bh[ks][fn], acc[fm][fn], 0, 0, 0);
        }
    __builtin_amdgcn_s_setprio(0);
    __builtin_amdgcn_sched_barrier(0);
  }

#pragma unroll
  for (int fm = 0; fm < 2; ++fm)
#pragma unroll
    for (int fn = 0; fn < 2; ++fn)
#pragma unroll
      for (int j = 0; j < 16; ++j) {
        const int row = brow + wm * 64 + fm * 32 + (j & 3) + 8 * (j >> 2) + 4 * (lane >> 5);
        const int col = bcol + wn * 64 + fn * 32 + (lane & 31);
        S[(size_t)row * N + col] = acc[fm][fn][j] * 0.03125f;
      }
}

// ---- generic BT-GEMM (m97-style): C[M][N] = A[M][K] . B[N][K]^T ----
template <int NM, int OUT>
__global__ __launch_bounds__(256) void gemm_bt(
    const f16* __restrict__ A, const f16* __restrict__ Al,
    const f16* __restrict__ B, const f16* __restrict__ Bl, int K,
    float* __restrict__ outf, f16* __restrict__ oh, f16* __restrict__ ol,
    int ldo, float scale) {
  f16* smem = (f16*)dsm;
  f16* tAh = smem;
  f16* tBh = smem + 8192;
  f16* tAl = smem + 16384;
  f16* tBl = smem + 24576;

  const int tid = threadIdx.x;
  const int lane = tid & 63, wid = tid >> 6;
  const int wr = wid >> 1, wc = wid & 1;
  const int brow = blockIdx.x * 128, bcol = blockIdx.y * 128;
  const int ar = lane & 15, k0 = (lane >> 4) * 8;
  const int crow = lane >> 3, ccol = (lane & 7) * 8;

  f32x4 acc[4][4] = {};
  const size_t aoff = (size_t)crow * K + ccol;

  for (int kt = 0; kt < K; kt += 64) {
    const f16* Ab = A + (size_t)brow * K + kt;
    const f16* Bb = B + (size_t)bcol * K + kt;
#pragma unroll
    for (int cc = 0; cc < 4; ++cc) {
      const int c = wid * 4 + cc;
      const size_t co = (size_t)c * 8 * K + aoff;
      gload16(Ab + co, tAh + c * 512);
      gload16(Bb + co, tBh + c * 512);
      if constexpr (NM == 3) {
        gload16(Al + (size_t)brow * K + kt + co, tAl + c * 512);
        gload16(Bl + (size_t)bcol * K + kt + co, tBl + c * 512);
      }
    }
    __syncthreads();
#pragma unroll
    for (int ks = 0; ks < 2; ++ks) {
      f16x8 ah[4], bh[4], alv[4], blv[4];
#pragma unroll
      for (int m = 0; m < 4; ++m) {
        ah[m] = *(const f16x8*)&tAh[(wr * 64 + m * 16 + ar) * 64 + ks * 32 + k0];
        bh[m] = *(const f16x8*)&tBh[(wc * 64 + m * 16 + ar) * 64 + ks * 32 + k0];
        if constexpr (NM == 3) {
          alv[m] = *(const f16x8*)&tAl[(wr * 64 + m * 16 + ar) * 64 + ks * 32 + k0];
          blv[m] = *(const f16x8*)&tBl[(wc * 64 + m * 16 + ar) * 64 + ks * 32 + k0];
        }
      }
#pragma unroll
      for (int m = 0; m < 4; ++m)
#pragma unroll
        for (int n = 0; n < 4; ++n) {
          acc[m][n] = __builtin_amdgcn_mfma_f32_16x16x32_f16(ah[m], bh[n], acc[m][n], 0, 0, 0);
          if constexpr (NM == 3) {
            acc[m][n] = __builtin_amdgcn_mfma_f32_16x16x32_f16(ah[m], blv[n], acc[m][n], 0, 0, 0);
            acc[m][n] = __builtin_amdgcn_mfma_f32_16x16x32_f16(alv[m], bh[n], acc[m][n], 0, 0, 0);
          }
        }
    }
    __syncthreads();
  }

#pragma unroll
  for (int m = 0; m < 4; ++m)
#pragma unroll
    for (int n = 0; n < 4; ++n)
#pragma unroll
      for (int j = 0; j < 4; ++j) {
        const int row = brow + wr * 64 + m * 16 + (lane >> 4) * 4 + j;
        const int col = bcol + wc * 64 + n * 16 + ar;
        const size_t idx = (size_t)row * ldo + col;
        const float v = acc[m][n][j] * scale;
        if constexpr (OUT == 0) {
          outf[idx] = v;
        } else if constexpr (OUT == 1) {
          f16 h, l;
          split_f32(v, h, l);
          oh[idx] = h;
          ol[idx] = l;
        } else {
          oh[idx] = (f16)v;
        }
      }
}

// ---- row softmax: S f32 [4096][4096] -> P f16 ----
__global__ __launch_bounds__(256) void k_softmax(const float* __restrict__ S,
                                                 f16* __restrict__ P) {
  const int row = blockIdx.x;
  const int tid = threadIdx.x;
  const int lane = tid & 63, wid = tid >> 6;
  const float* s = S + (size_t)row * 4096;
  float4 v[4];
#pragma unroll
  for (int i = 0; i < 4; ++i) v[i] = ((const float4*)s)[tid + 256 * i];

  float mx = -3.4e38f;
#pragma unroll
  for (int i = 0; i < 4; ++i)
    mx = fmaxf(mx, fmaxf(fmaxf(v[i].x, v[i].y), fmaxf(v[i].z, v[i].w)));
#pragma unroll
  for (int off = 1; off < 64; off <<= 1) mx = fmaxf(mx, __shfl_xor(mx, off, 64));
  __shared__ float red[4];
  if (lane == 0) red[wid] = mx;
  __syncthreads();
  mx = fmaxf(fmaxf(red[0], red[1]), fmaxf(red[2], red[3]));

  float sum = 0.f;
#pragma unroll
  for (int i = 0; i < 4; ++i) {
    v[i].x = __expf(v[i].x - mx); v[i].y = __expf(v[i].y - mx);
    v[i].z = __expf(v[i].z - mx); v[i].w = __expf(v[i].w - mx);
    sum += v[i].x + v[i].y + v[i].z + v[i].w;
  }
#pragma unroll
  for (int off = 1; off < 64; off <<= 1) sum += __shfl_xor(sum, off, 64);
  __syncthreads();
  if (lane == 0) red[wid] = sum;
  __syncthreads();
  sum = red[0] + red[1] + red[2] + red[3];
  const float inv = 1.0f / sum;

  f16* p = P + (size_t)row * 4096;
#pragma unroll
  for (int i = 0; i < 4; ++i) {
    f16x4v pv;
    pv[0] = (f16)(v[i].x * inv); pv[1] = (f16)(v[i].y * inv);
    pv[2] = (f16)(v[i].z * inv); pv[3] = (f16)(v[i].w * inv);
    ((f16x4v*)p)[tid + 256 * i] = pv;
  }
}

extern "C" void kernel_launch(void* const* d_in, const int* in_sizes, int n_in,
                              void* d_out, int out_size, void* d_ws,
                              size_t ws_size, hipStream_t stream) {
  const float* x = (const float*)d_in[0];
  const float* Wq = (const float*)d_in[1];
  const float* Wk = (const float*)d_in[2];
  const float* Wv = (const float*)d_in[3];
  float* out = (float*)d_out;
  char* ws = (char*)d_ws;
  const size_t MiB = 1u << 20;
  f16* Qh = (f16*)(ws + 0 * MiB);
  f16* Ql = (f16*)(ws + 8 * MiB);
  f16* Kh = (f16*)(ws + 16 * MiB);
  f16* Kl = (f16*)(ws + 24 * MiB);
  f16* Vt = (f16*)(ws + 32 * MiB);
  float* S = (float*)(ws + 40 * MiB);  // 64 MiB
  f16* Pm = (f16*)(ws + 0 * MiB);      // reuses dead Q/K
  f16* xh = (f16*)(ws + 40 * MiB);
  f16* xl = (f16*)(ws + 48 * MiB);
  f16* Wtqh = (f16*)(ws + 56 * MiB);
  f16* Wtql = (f16*)(ws + 58 * MiB);
  f16* Wtkh = (f16*)(ws + 60 * MiB);
  f16* Wtkl = (f16*)(ws + 62 * MiB);
  f16* Wtvh = (f16*)(ws + 64 * MiB);
  f16* Wtvl = (f16*)(ws + 66 * MiB);

  // allow 144 KiB dynamic LDS for the pipelined QK^T (idempotent, capture-safe)
  (void)hipFuncSetAttribute((const void*)k_qkt,
                            hipFuncAttributeMaxDynamicSharedMemorySize,
                            3 * 49152);

  k_wsplit<<<dim3(16, 16, 3), 256, 0, stream>>>(Wq, Wk, Wv, Wtqh, Wtql, Wtkh,
                                                Wtkl, Wtvh, Wtvl);
  k_xsplit<<<dim3(4096), 256, 0, stream>>>(x, xh, xl);
  gemm_bt<3, 1><<<dim3(32, 8), 256, 65536, stream>>>(
      xh, xl, Wtqh, Wtql, 1024, nullptr, Qh, Ql, 1024, 1.0f);
  gemm_bt<3, 1><<<dim3(32, 8), 256, 65536, stream>>>(
      xh, xl, Wtkh, Wtkl, 1024, nullptr, Kh, Kl, 1024, 1.0f);
  gemm_bt<1, 2><<<dim3(8, 32), 256, 32768, stream>>>(
      Wtvh, nullptr, xh, nullptr, 1024, nullptr, Vt, nullptr, 4096, 1.0f);
  k_qkt<<<dim3(512), 512, 3 * 49152, stream>>>(Qh, Ql, Kh, Kl, S);
  k_softmax<<<dim3(4096), 256, 0, stream>>>(S, Pm);
  gemm_bt<1, 0><<<dim3(32, 8), 256, 32768, stream>>>(
      Pm, nullptr, Vt, nullptr, 4096, out, nullptr, nullptr, 1024, 1.0f);
}

// Round 5
// 311.714 us; speedup vs baseline: 1.0584x; 1.0584x over previous
//
#include <hip/hip_runtime.h>

// SelfAttention: out = softmax((xWq)(xWk)^T/32) @ (xWv), f32, S=4096, D=1024.
// Q,K and QK^T in fp16 hi/lo split (3-MFMA); V path single MFMA.
// R5: k_qkt reworked: 256x256 tile, 8 waves x (128x64), BK=32, 2 LDS buffers,
// 2 phases/iter with staging+ds_read interleaved under MFMA execution,
// counted vmcnt(4), raw barriers, swizzled LDS, setprio, XCD swizzle.
// ws layout (MiB): Qh 0, Ql 8, Kh 16, Kl 24, Vt 32, S 40..104 (f32)
//   P 0..32 (reuses dead Q/K); temps in dead S region: xh 40, xl 48, Wt* 56..68

typedef _Float16 f16;
typedef f16 f16x8 __attribute__((ext_vector_type(8)));
typedef f16 f16x4v __attribute__((ext_vector_type(4)));
typedef float f32x4 __attribute__((ext_vector_type(4)));
typedef float f32x16 __attribute__((ext_vector_type(16)));
typedef unsigned short u16;
typedef u16 u16x8 __attribute__((ext_vector_type(8)));

extern __shared__ char dsm[];  // single dynamic-LDS symbol for the whole TU

__device__ __forceinline__ void split_f32(float v, f16& h, f16& l) {
  h = (f16)v;
  l = (f16)(v - (float)h);
}

__device__ __forceinline__ void gload16(const void* g, void* l) {
  __builtin_amdgcn_global_load_lds(
      (const __attribute__((address_space(1))) void*)g,
      (__attribute__((address_space(3))) void*)l, 16, 0, 0);
}

// ---- prep: split x -> xh, xl (f16) ----
__global__ __launch_bounds__(256) void k_xsplit(const float* __restrict__ x,
                                                f16* __restrict__ xh,
                                                f16* __restrict__ xl) {
  const size_t i = ((size_t)blockIdx.x * 256 + threadIdx.x) * 4;
  float4 f = *(const float4*)&x[i];
  f16x4v h, l;
  f16 hh, ll;
  split_f32(f.x, hh, ll); h[0] = hh; l[0] = ll;
  split_f32(f.y, hh, ll); h[1] = hh; l[1] = ll;
  split_f32(f.z, hh, ll); h[2] = hh; l[2] = ll;
  split_f32(f.w, hh, ll); h[3] = hh; l[3] = ll;
  *(f16x4v*)&xh[i] = h;
  *(f16x4v*)&xl[i] = l;
}

// ---- prep: transpose+split W [k][n] f32 -> Wt_h, Wt_l [n][k] f16 ----
__global__ __launch_bounds__(256) void k_wsplit(
    const float* __restrict__ Wq, const float* __restrict__ Wk,
    const float* __restrict__ Wv, f16* __restrict__ qh, f16* __restrict__ ql,
    f16* __restrict__ kh, f16* __restrict__ kl, f16* __restrict__ vh,
    f16* __restrict__ vl) {
  __shared__ float sh[64][65];
  const int z = blockIdx.z;
  const float* __restrict__ W = (z == 0) ? Wq : (z == 1) ? Wk : Wv;
  f16* __restrict__ oh = (z == 0) ? qh : (z == 1) ? kh : vh;
  f16* __restrict__ ol = (z == 0) ? ql : (z == 1) ? kl : vl;
  const int kb = blockIdx.x * 64, nb = blockIdx.y * 64;
  const int t = threadIdx.x;
  const int r = t >> 2, c4 = (t & 3) * 16;
#pragma unroll
  for (int i = 0; i < 4; ++i) {
    float4 f = *(const float4*)&W[(size_t)(kb + r) * 1024 + nb + c4 + i * 4];
    sh[r][c4 + i * 4 + 0] = f.x;
    sh[r][c4 + i * 4 + 1] = f.y;
    sh[r][c4 + i * 4 + 2] = f.z;
    sh[r][c4 + i * 4 + 3] = f.w;
  }
  __syncthreads();
  const int n = t >> 2, ks = (t & 3) * 16;
  u16x8 h0, h1, l0, l1;
#pragma unroll
  for (int i = 0; i < 8; ++i) {
    f16 h, l;
    split_f32(sh[ks + i][n], h, l);
    h0[i] = __builtin_bit_cast(u16, h);
    l0[i] = __builtin_bit_cast(u16, l);
    split_f32(sh[ks + 8 + i][n], h, l);
    h1[i] = __builtin_bit_cast(u16, h);
    l1[i] = __builtin_bit_cast(u16, l);
  }
  const size_t o = (size_t)(nb + n) * 1024 + kb + ks;
  *(u16x8*)&oh[o] = h0;
  *(u16x8*)&oh[o + 8] = h1;
  *(u16x8*)&ol[o] = l0;
  *(u16x8*)&ol[o + 8] = l1;
}

// ---- QK^T: S = (Q.K^T)/32, 256x256 tile, 2-buffer 2-phase pipeline ----
// LDS buffer (64 KiB): Ah[0,16K) Al[16K,32K) Bh[32K,48K) Bl[48K,64K).
// Rows of 64 B; 16B-slot swizzle: slot ^= (row>>1)&3 (on global src + ds_read).
__global__ __launch_bounds__(512, 2) void k_qkt(
    const f16* __restrict__ Qh, const f16* __restrict__ Ql,
    const f16* __restrict__ Kh, const f16* __restrict__ Kl,
    float* __restrict__ S) {
  char* smem = dsm;
  constexpr int K = 1024, N = 4096, nT = 32;
  const int tid = threadIdx.x;
  const int lane = tid & 63, wv = tid >> 6;
  const int wm = wv >> 2, wn = wv & 3;  // 2x4 waves, each 128x64
  const int bid = blockIdx.x;           // 256 blocks
  const int wg = (bid & 7) * 32 + (bid >> 3);  // bijective XCD swizzle
  const int bx = wg >> 4, by = wg & 15;        // 16 x 16
  const int brow = bx * 256, bcol = by * 256;

  // staging: wave wv covers region wv>>1 (0=Ah,1=Al,2=Bh,3=Bl), 8 instrs
  const int sreg = wv >> 1;
  const f16* __restrict__ sbase = (sreg == 0) ? Qh : (sreg == 1) ? Ql
                                  : (sreg == 2) ? Kh : Kl;
  const int srbase = (sreg >= 2) ? bcol : brow;
  const int srow16 = lane >> 2;                            // 0..15 within group
  const int sslot = (lane & 3) ^ ((lane >> 3) & 3);        // inv-swizzled slot

  auto stage_part = [&](int buf, int t, int jj0) {
    const int kt = t * 32;
    char* rb = smem + 65536 * buf + sreg * 16384;
#pragma unroll
    for (int j = 0; j < 4; ++j) {
      const int g = (wv & 1) * 8 + jj0 + j;  // 0..15 row-group
      gload16(sbase + (size_t)(srbase + 16 * g + srow16) * K + kt + 8 * sslot,
              rb + g * 1024);
    }
  };

  f32x16 acc[4][2] = {};
  const int l31 = lane & 31, ch0 = lane >> 5;
  const int arow0 = wm * 128 + l31;  // + fm*32
  const int brow0 = wn * 64 + l31;   // + fn*32
  const int pA = (l31 >> 1) & 3;     // swizzle pattern (row>>1)&3, row-dependent part

  stage_part(0, 0, 0);
  stage_part(0, 0, 4);

  for (int t = 0; t < nT; ++t) {
    const int cur = t & 1, nb = cur ^ 1;
    if (t < nT - 1) {
      stage_part(nb, t + 1, 0);  // 4 loads: first half of next tile
      asm volatile("s_waitcnt vmcnt(4)" ::: "memory");  // stage(t) landed (mine)
    } else {
      asm volatile("s_waitcnt vmcnt(0)" ::: "memory");
    }
    __builtin_amdgcn_sched_barrier(0);
    __builtin_amdgcn_s_barrier();  // everyone's stage(t) landed
    __builtin_amdgcn_sched_barrier(0);
    const char* bb = smem + 65536 * cur;

#pragma unroll
    for (int ks = 0; ks < 2; ++ks) {
      if (ks == 1 && t < nT - 1) stage_part(nb, t + 1, 4);  // second half
      const int ch = ks * 2 + ch0;
      f16x8 ah[4], al[4], bh[2], bl[2];
#pragma unroll
      for (int fm = 0; fm < 4; ++fm) {
        const int r = arow0 + fm * 32;
        const int off = r * 64 + 16 * ((ch ^ pA));
        ah[fm] = *(const f16x8*)(bb + off);
        al[fm] = *(const f16x8*)(bb + 16384 + off);
      }
#pragma unroll
      for (int fn = 0; fn < 2; ++fn) {
        const int r = brow0 + fn * 32;
        const int off = r * 64 + 16 * ((ch ^ pA));
        bh[fn] = *(const f16x8*)(bb + 32768 + off);
        bl[fn] = *(const f16x8*)(bb + 49152 + off);
      }
      __builtin_amdgcn_s_setprio(1);
#pragma unroll
      for (int fm = 0; fm < 4; ++fm)
#pragma unroll
        for (int fn = 0; fn < 2; ++fn) {
          acc[fm][fn] = __builtin_amdgcn_mfma_f32_32x32x16_f16(
              ah[fm], bh[fn], acc[fm][fn], 0, 0, 0);
          acc[fm][fn] = __builtin_amdgcn_mfma_f32_32x32x16_f16(
              ah[fm], bl[fn], acc[fm][fn], 0, 0, 0);
          acc[fm][fn] = __builtin_amdgcn_mfma_f32_32x32x16_f16(
              al[fm], bh[fn], acc[fm][fn], 0, 0, 0);
        }
      __builtin_amdgcn_s_setprio(0);
    }
    __builtin_amdgcn_sched_barrier(0);
    __builtin_amdgcn_s_barrier();  // all reads of buf cur drained
  }

#pragma unroll
  for (int fm = 0; fm < 4; ++fm)
#pragma unroll
    for (int fn = 0; fn < 2; ++fn)
#pragma unroll
      for (int j = 0; j < 16; ++j) {
        const int row =
            brow + wm * 128 + fm * 32 + (j & 3) + 8 * (j >> 2) + 4 * ch0;
        const int col = bcol + wn * 64 + fn * 32 + l31;
        S[(size_t)row * N + col] = acc[fm][fn][j] * 0.03125f;
      }
}

// ---- generic BT-GEMM (m97-style): C[M][N] = A[M][K] . B[N][K]^T ----
template <int NM, int OUT>
__global__ __launch_bounds__(256) void gemm_bt(
    const f16* __restrict__ A, const f16* __restrict__ Al,
    const f16* __restrict__ B, const f16* __restrict__ Bl, int K,
    float* __restrict__ outf, f16* __restrict__ oh, f16* __restrict__ ol,
    int ldo, float scale) {
  f16* smem = (f16*)dsm;
  f16* tAh = smem;
  f16* tBh = smem + 8192;
  f16* tAl = smem + 16384;
  f16* tBl = smem + 24576;

  const int tid = threadIdx.x;
  const int lane = tid & 63, wid = tid >> 6;
  const int wr = wid >> 1, wc = wid & 1;
  const int brow = blockIdx.x * 128, bcol = blockIdx.y * 128;
  const int ar = lane & 15, k0 = (lane >> 4) * 8;
  const int crow = lane >> 3, ccol = (lane & 7) * 8;

  f32x4 acc[4][4] = {};
  const size_t aoff = (size_t)crow * K + ccol;

  for (int kt = 0; kt < K; kt += 64) {
    const f16* Ab = A + (size_t)brow * K + kt;
    const f16* Bb = B + (size_t)bcol * K + kt;
#pragma unroll
    for (int cc = 0; cc < 4; ++cc) {
      const int c = wid * 4 + cc;
      const size_t co = (size_t)c * 8 * K + aoff;
      gload16(Ab + co, tAh + c * 512);
      gload16(Bb + co, tBh + c * 512);
      if constexpr (NM == 3) {
        gload16(Al + (size_t)brow * K + kt + co, tAl + c * 512);
        gload16(Bl + (size_t)bcol * K + kt + co, tBl + c * 512);
      }
    }
    __syncthreads();
#pragma unroll
    for (int ks = 0; ks < 2; ++ks) {
      f16x8 ah[4], bh[4], alv[4], blv[4];
#pragma unroll
      for (int m = 0; m < 4; ++m) {
        ah[m] = *(const f16x8*)&tAh[(wr * 64 + m * 16 + ar) * 64 + ks * 32 + k0];
        bh[m] = *(const f16x8*)&tBh[(wc * 64 + m * 16 + ar) * 64 + ks * 32 + k0];
        if constexpr (NM == 3) {
          alv[m] = *(const f16x8*)&tAl[(wr * 64 + m * 16 + ar) * 64 + ks * 32 + k0];
          blv[m] = *(const f16x8*)&tBl[(wc * 64 + m * 16 + ar) * 64 + ks * 32 + k0];
        }
      }
#pragma unroll
      for (int m = 0; m < 4; ++m)
#pragma unroll
        for (int n = 0; n < 4; ++n) {
          acc[m][n] = __builtin_amdgcn_mfma_f32_16x16x32_f16(ah[m], bh[n], acc[m][n], 0, 0, 0);
          if constexpr (NM == 3) {
            acc[m][n] = __builtin_amdgcn_mfma_f32_16x16x32_f16(ah[m], blv[n], acc[m][n], 0, 0, 0);
            acc[m][n] = __builtin_amdgcn_mfma_f32_16x16x32_f16(alv[m], bh[n], acc[m][n], 0, 0, 0);
          }
        }
    }
    __syncthreads();
  }

#pragma unroll
  for (int m = 0; m < 4; ++m)
#pragma unroll
    for (int n = 0; n < 4; ++n)
#pragma unroll
      for (int j = 0; j < 4; ++j) {
        const int row = brow + wr * 64 + m * 16 + (lane >> 4) * 4 + j;
        const int col = bcol + wc * 64 + n * 16 + ar;
        const size_t idx = (size_t)row * ldo + col;
        const float v = acc[m][n][j] * scale;
        if constexpr (OUT == 0) {
          outf[idx] = v;
        } else if constexpr (OUT == 1) {
          f16 h, l;
          split_f32(v, h, l);
          oh[idx] = h;
          ol[idx] = l;
        } else {
          oh[idx] = (f16)v;
        }
      }
}

// ---- row softmax: S f32 [4096][4096] -> P f16 ----
__global__ __launch_bounds__(256) void k_softmax(const float* __restrict__ S,
                                                 f16* __restrict__ P) {
  const int row = blockIdx.x;
  const int tid = threadIdx.x;
  const int lane = tid & 63, wid = tid >> 6;
  const float* s = S + (size_t)row * 4096;
  float4 v[4];
#pragma unroll
  for (int i = 0; i < 4; ++i) v[i] = ((const float4*)s)[tid + 256 * i];

  float mx = -3.4e38f;
#pragma unroll
  for (int i = 0; i < 4; ++i)
    mx = fmaxf(mx, fmaxf(fmaxf(v[i].x, v[i].y), fmaxf(v[i].z, v[i].w)));
#pragma unroll
  for (int off = 1; off < 64; off <<= 1) mx = fmaxf(mx, __shfl_xor(mx, off, 64));
  __shared__ float red[4];
  if (lane == 0) red[wid] = mx;
  __syncthreads();
  mx = fmaxf(fmaxf(red[0], red[1]), fmaxf(red[2], red[3]));

  float sum = 0.f;
#pragma unroll
  for (int i = 0; i < 4; ++i) {
    v[i].x = __expf(v[i].x - mx); v[i].y = __expf(v[i].y - mx);
    v[i].z = __expf(v[i].z - mx); v[i].w = __expf(v[i].w - mx);
    sum += v[i].x + v[i].y + v[i].z + v[i].w;
  }
#pragma unroll
  for (int off = 1; off < 64; off <<= 1) sum += __shfl_xor(sum, off, 64);
  __syncthreads();
  if (lane == 0) red[wid] = sum;
  __syncthreads();
  sum = red[0] + red[1] + red[2] + red[3];
  const float inv = 1.0f / sum;

  f16* p = P + (size_t)row * 4096;
#pragma unroll
  for (int i = 0; i < 4; ++i) {
    f16x4v pv;
    pv[0] = (f16)(v[i].x * inv); pv[1] = (f16)(v[i].y * inv);
    pv[2] = (f16)(v[i].z * inv); pv[3] = (f16)(v[i].w * inv);
    ((f16x4v*)p)[tid + 256 * i] = pv;
  }
}

extern "C" void kernel_launch(void* const* d_in, const int* in_sizes, int n_in,
                              void* d_out, int out_size, void* d_ws,
                              size_t ws_size, hipStream_t stream) {
  const float* x = (const float*)d_in[0];
  const float* Wq = (const float*)d_in[1];
  const float* Wk = (const float*)d_in[2];
  const float* Wv = (const float*)d_in[3];
  float* out = (float*)d_out;
  char* ws = (char*)d_ws;
  const size_t MiB = 1u << 20;
  f16* Qh = (f16*)(ws + 0 * MiB);
  f16* Ql = (f16*)(ws + 8 * MiB);
  f16* Kh = (f16*)(ws + 16 * MiB);
  f16* Kl = (f16*)(ws + 24 * MiB);
  f16* Vt = (f16*)(ws + 32 * MiB);
  float* S = (float*)(ws + 40 * MiB);  // 64 MiB
  f16* Pm = (f16*)(ws + 0 * MiB);      // reuses dead Q/K
  f16* xh = (f16*)(ws + 40 * MiB);
  f16* xl = (f16*)(ws + 48 * MiB);
  f16* Wtqh = (f16*)(ws + 56 * MiB);
  f16* Wtql = (f16*)(ws + 58 * MiB);
  f16* Wtkh = (f16*)(ws + 60 * MiB);
  f16* Wtkl = (f16*)(ws + 62 * MiB);
  f16* Wtvh = (f16*)(ws + 64 * MiB);
  f16* Wtvl = (f16*)(ws + 66 * MiB);

  // allow 128 KiB dynamic LDS for the pipelined QK^T (idempotent, capture-safe)
  (void)hipFuncSetAttribute((const void*)k_qkt,
                            hipFuncAttributeMaxDynamicSharedMemorySize,
                            131072);

  k_wsplit<<<dim3(16, 16, 3), 256, 0, stream>>>(Wq, Wk, Wv, Wtqh, Wtql, Wtkh,
                                                Wtkl, Wtvh, Wtvl);
  k_xsplit<<<dim3(4096), 256, 0, stream>>>(x, xh, xl);
  gemm_bt<3, 1><<<dim3(32, 8), 256, 65536, stream>>>(
      xh, xl, Wtqh, Wtql, 1024, nullptr, Qh, Ql, 1024, 1.0f);
  gemm_bt<3, 1><<<dim3(32, 8), 256, 65536, stream>>>(
      xh, xl, Wtkh, Wtkl, 1024, nullptr, Kh, Kl, 1024, 1.0f);
  gemm_bt<1, 2><<<dim3(8, 32), 256, 32768, stream>>>(
      Wtvh, nullptr, xh, nullptr, 1024, nullptr, Vt, nullptr, 4096, 1.0f);
  k_qkt<<<dim3(256), 512, 131072, stream>>>(Qh, Ql, Kh, Kl, S);
  k_softmax<<<dim3(4096), 256, 0, stream>>>(S, Pm);
  gemm_bt<1, 0><<<dim3(32, 8), 256, 32768, stream>>>(
      Pm, nullptr, Vt, nullptr, 4096, out, nullptr, nullptr, 1024, 1.0f);
}

// Round 6
// 306.823 us; speedup vs baseline: 1.0752x; 1.0159x over previous
//
#include <hip/hip_runtime.h>

// SelfAttention: out = softmax((xWq)(xWk)^T/32) @ (xWv), f32, S=4096, D=1024.
// R6 restructure: QK^T = x·(Wq·Wk^T)·x^T.
//   Mt[b][a] = (1/32)·sum_q Wk[b,q]·Wq[a,q]   (BT-GEMM of raw W rows, 1024^3)
//   T = x·(M/32)  (BT-GEMM A=x, B=Mt, 4096x1024x1024, split f16 out)
//   S = T·x^T     (pipelined k_qkt kernel, A=T split, B=x split)
// All high-precision GEMMs use fp16 hi/lo split 3-MFMA; V path single MFMA.
// ws layout (MiB): xh 0, xl 8, Th 16, Tl 24, Vt 32, S 40..104 (f32)
//   P 0..32 (over dead xh/xl/Th/Tl after S); temps in dead-S region:
//   Wqh 40, Wql 42, Wkh 44, Wkl 46, Mth 48, Mtl 50, Wtvh 52.

typedef _Float16 f16;
typedef f16 f16x8 __attribute__((ext_vector_type(8)));
typedef f16 f16x4v __attribute__((ext_vector_type(4)));
typedef float f32x4 __attribute__((ext_vector_type(4)));
typedef float f32x16 __attribute__((ext_vector_type(16)));
typedef unsigned short u16;
typedef u16 u16x8 __attribute__((ext_vector_type(8)));

extern __shared__ char dsm[];  // single dynamic-LDS symbol for the whole TU

__device__ __forceinline__ void split_f32(float v, f16& h, f16& l) {
  h = (f16)v;
  l = (f16)(v - (float)h);
}

__device__ __forceinline__ void gload16(const void* g, void* l) {
  __builtin_amdgcn_global_load_lds(
      (const __attribute__((address_space(1))) void*)g,
      (__attribute__((address_space(3))) void*)l, 16, 0, 0);
}

// ---- prep: elementwise split f32 -> (h,l) f16 for x, Wq, Wk ----
__global__ __launch_bounds__(256) void k_split(
    const float* __restrict__ x, const float* __restrict__ wq,
    const float* __restrict__ wk, f16* __restrict__ xh, f16* __restrict__ xl,
    f16* __restrict__ qh, f16* __restrict__ ql, f16* __restrict__ kh,
    f16* __restrict__ kl) {
  const int z = blockIdx.z;
  const float* __restrict__ src = (z == 0) ? x : (z == 1) ? wq : wk;
  f16* __restrict__ oh = (z == 0) ? xh : (z == 1) ? qh : kh;
  f16* __restrict__ ol = (z == 0) ? xl : (z == 1) ? ql : kl;
  const int n4 = (z == 0) ? (4096 * 1024 / 4) : (1024 * 1024 / 4);
  for (int i = blockIdx.x * 256 + threadIdx.x; i < n4; i += 1024 * 256) {
    float4 f = ((const float4*)src)[i];
    f16x4v h, l;
    f16 hh, ll;
    split_f32(f.x, hh, ll); h[0] = hh; l[0] = ll;
    split_f32(f.y, hh, ll); h[1] = hh; l[1] = ll;
    split_f32(f.z, hh, ll); h[2] = hh; l[2] = ll;
    split_f32(f.w, hh, ll); h[3] = hh; l[3] = ll;
    ((f16x4v*)oh)[i] = h;
    ((f16x4v*)ol)[i] = l;
  }
}

// ---- prep: transpose+split-h Wv [a][d] f32 -> Wtvh [d][a] f16 ----
__global__ __launch_bounds__(256) void k_wsplit_v(const float* __restrict__ Wv,
                                                  f16* __restrict__ vt) {
  __shared__ float sh[64][65];
  const int kb = blockIdx.x * 64, nb = blockIdx.y * 64;
  const int t = threadIdx.x;
  const int r = t >> 2, c4 = (t & 3) * 16;
#pragma unroll
  for (int i = 0; i < 4; ++i) {
    float4 f = *(const float4*)&Wv[(size_t)(kb + r) * 1024 + nb + c4 + i * 4];
    sh[r][c4 + i * 4 + 0] = f.x;
    sh[r][c4 + i * 4 + 1] = f.y;
    sh[r][c4 + i * 4 + 2] = f.z;
    sh[r][c4 + i * 4 + 3] = f.w;
  }
  __syncthreads();
  const int n = t >> 2, ks = (t & 3) * 16;
  u16x8 h0, h1;
#pragma unroll
  for (int i = 0; i < 8; ++i) {
    h0[i] = __builtin_bit_cast(u16, (f16)sh[ks + i][n]);
    h1[i] = __builtin_bit_cast(u16, (f16)sh[ks + 8 + i][n]);
  }
  const size_t o = (size_t)(nb + n) * 1024 + kb + ks;
  *(u16x8*)&vt[o] = h0;
  *(u16x8*)&vt[o + 8] = h1;
}

// ---- S = T·x^T: 256x256 tile, 2-buffer 2-phase pipeline, split 3-MFMA ----
// LDS buffer (64 KiB): Ah[0,16K) Al[16K,32K) Bh[32K,48K) Bl[48K,64K).
// Rows of 64 B; 16B-slot swizzle: slot ^= (row>>1)&3 (on global src + ds_read).
__global__ __launch_bounds__(512, 2) void k_qkt(
    const f16* __restrict__ Ah, const f16* __restrict__ Al,
    const f16* __restrict__ Bh, const f16* __restrict__ Bl,
    float* __restrict__ S) {
  char* smem = dsm;
  constexpr int K = 1024, N = 4096, nT = 32;
  const int tid = threadIdx.x;
  const int lane = tid & 63, wv = tid >> 6;
  const int wm = wv >> 2, wn = wv & 3;  // 2x4 waves, each 128x64
  const int bid = blockIdx.x;           // 256 blocks
  const int wg = (bid & 7) * 32 + (bid >> 3);  // bijective XCD swizzle
  const int bx = wg >> 4, by = wg & 15;        // 16 x 16
  const int brow = bx * 256, bcol = by * 256;

  // staging: wave wv covers region wv>>1 (0=Ah,1=Al,2=Bh,3=Bl), 8 instrs
  const int sreg = wv >> 1;
  const f16* __restrict__ sbase = (sreg == 0) ? Ah : (sreg == 1) ? Al
                                  : (sreg == 2) ? Bh : Bl;
  const int srbase = (sreg >= 2) ? bcol : brow;
  const int srow16 = lane >> 2;                            // 0..15 within group
  const int sslot = (lane & 3) ^ ((lane >> 3) & 3);        // inv-swizzled slot

  auto stage_part = [&](int buf, int t, int jj0) {
    const int kt = t * 32;
    char* rb = smem + 65536 * buf + sreg * 16384;
#pragma unroll
    for (int j = 0; j < 4; ++j) {
      const int g = (wv & 1) * 8 + jj0 + j;  // 0..15 row-group
      gload16(sbase + (size_t)(srbase + 16 * g + srow16) * K + kt + 8 * sslot,
              rb + g * 1024);
    }
  };

  f32x16 acc[4][2] = {};
  const int l31 = lane & 31, ch0 = lane >> 5;
  const int arow0 = wm * 128 + l31;  // + fm*32
  const int brow0 = wn * 64 + l31;   // + fn*32
  const int pA = (l31 >> 1) & 3;     // swizzle pattern (row>>1)&3

  stage_part(0, 0, 0);
  stage_part(0, 0, 4);

  for (int t = 0; t < nT; ++t) {
    const int cur = t & 1, nb = cur ^ 1;
    if (t < nT - 1) {
      stage_part(nb, t + 1, 0);  // 4 loads: first half of next tile
      asm volatile("s_waitcnt vmcnt(4)" ::: "memory");  // stage(t) landed (mine)
    } else {
      asm volatile("s_waitcnt vmcnt(0)" ::: "memory");
    }
    __builtin_amdgcn_sched_barrier(0);
    __builtin_amdgcn_s_barrier();  // everyone's stage(t) landed
    __builtin_amdgcn_sched_barrier(0);
    const char* bb = smem + 65536 * cur;

#pragma unroll
    for (int ks = 0; ks < 2; ++ks) {
      if (ks == 1 && t < nT - 1) stage_part(nb, t + 1, 4);  // second half
      const int ch = ks * 2 + ch0;
      f16x8 ah[4], al[4], bh[2], bl[2];
#pragma unroll
      for (int fm = 0; fm < 4; ++fm) {
        const int r = arow0 + fm * 32;
        const int off = r * 64 + 16 * ((ch ^ pA));
        ah[fm] = *(const f16x8*)(bb + off);
        al[fm] = *(const f16x8*)(bb + 16384 + off);
      }
#pragma unroll
      for (int fn = 0; fn < 2; ++fn) {
        const int r = brow0 + fn * 32;
        const int off = r * 64 + 16 * ((ch ^ pA));
        bh[fn] = *(const f16x8*)(bb + 32768 + off);
        bl[fn] = *(const f16x8*)(bb + 49152 + off);
      }
      __builtin_amdgcn_s_setprio(1);
#pragma unroll
      for (int fm = 0; fm < 4; ++fm)
#pragma unroll
        for (int fn = 0; fn < 2; ++fn) {
          acc[fm][fn] = __builtin_amdgcn_mfma_f32_32x32x16_f16(
              ah[fm], bh[fn], acc[fm][fn], 0, 0, 0);
          acc[fm][fn] = __builtin_amdgcn_mfma_f32_32x32x16_f16(
              ah[fm], bl[fn], acc[fm][fn], 0, 0, 0);
          acc[fm][fn] = __builtin_amdgcn_mfma_f32_32x32x16_f16(
              al[fm], bh[fn], acc[fm][fn], 0, 0, 0);
        }
      __builtin_amdgcn_s_setprio(0);
    }
    __builtin_amdgcn_sched_barrier(0);
    __builtin_amdgcn_s_barrier();  // all reads of buf cur drained
  }

#pragma unroll
  for (int fm = 0; fm < 4; ++fm)
#pragma unroll
    for (int fn = 0; fn < 2; ++fn)
#pragma unroll
      for (int j = 0; j < 16; ++j) {
        const int row =
            brow + wm * 128 + fm * 32 + (j & 3) + 8 * (j >> 2) + 4 * ch0;
        const int col = bcol + wn * 64 + fn * 32 + l31;
        S[(size_t)row * N + col] = acc[fm][fn][j];  // scale folded into Mt
      }
}

// ---- generic BT-GEMM (m97-style): C[M][N] = A[M][K] . B[N][K]^T ----
template <int NM, int OUT>
__global__ __launch_bounds__(256) void gemm_bt(
    const f16* __restrict__ A, const f16* __restrict__ Al,
    const f16* __restrict__ B, const f16* __restrict__ Bl, int K,
    float* __restrict__ outf, f16* __restrict__ oh, f16* __restrict__ ol,
    int ldo, float scale) {
  f16* smem = (f16*)dsm;
  f16* tAh = smem;
  f16* tBh = smem + 8192;
  f16* tAl = smem + 16384;
  f16* tBl = smem + 24576;

  const int tid = threadIdx.x;
  const int lane = tid & 63, wid = tid >> 6;
  const int wr = wid >> 1, wc = wid & 1;
  const int brow = blockIdx.x * 128, bcol = blockIdx.y * 128;
  const int ar = lane & 15, k0 = (lane >> 4) * 8;
  const int crow = lane >> 3, ccol = (lane & 7) * 8;

  f32x4 acc[4][4] = {};
  const size_t aoff = (size_t)crow * K + ccol;

  for (int kt = 0; kt < K; kt += 64) {
    const f16* Ab = A + (size_t)brow * K + kt;
    const f16* Bb = B + (size_t)bcol * K + kt;
#pragma unroll
    for (int cc = 0; cc < 4; ++cc) {
      const int c = wid * 4 + cc;
      const size_t co = (size_t)c * 8 * K + aoff;
      gload16(Ab + co, tAh + c * 512);
      gload16(Bb + co, tBh + c * 512);
      if constexpr (NM == 3) {
        gload16(Al + (size_t)brow * K + kt + co, tAl + c * 512);
        gload16(Bl + (size_t)bcol * K + kt + co, tBl + c * 512);
      }
    }
    __syncthreads();
#pragma unroll
    for (int ks = 0; ks < 2; ++ks) {
      f16x8 ah[4], bh[4], alv[4], blv[4];
#pragma unroll
      for (int m = 0; m < 4; ++m) {
        ah[m] = *(const f16x8*)&tAh[(wr * 64 + m * 16 + ar) * 64 + ks * 32 + k0];
        bh[m] = *(const f16x8*)&tBh[(wc * 64 + m * 16 + ar) * 64 + ks * 32 + k0];
        if constexpr (NM == 3) {
          alv[m] = *(const f16x8*)&tAl[(wr * 64 + m * 16 + ar) * 64 + ks * 32 + k0];
          blv[m] = *(const f16x8*)&tBl[(wc * 64 + m * 16 + ar) * 64 + ks * 32 + k0];
        }
      }
#pragma unroll
      for (int m = 0; m < 4; ++m)
#pragma unroll
        for (int n = 0; n < 4; ++n) {
          acc[m][n] = __builtin_amdgcn_mfma_f32_16x16x32_f16(ah[m], bh[n], acc[m][n], 0, 0, 0);
          if constexpr (NM == 3) {
            acc[m][n] = __builtin_amdgcn_mfma_f32_16x16x32_f16(ah[m], blv[n], acc[m][n], 0, 0, 0);
            acc[m][n] = __builtin_amdgcn_mfma_f32_16x16x32_f16(alv[m], bh[n], acc[m][n], 0, 0, 0);
          }
        }
    }
    __syncthreads();
  }

#pragma unroll
  for (int m = 0; m < 4; ++m)
#pragma unroll
    for (int n = 0; n < 4; ++n)
#pragma unroll
      for (int j = 0; j < 4; ++j) {
        const int row = brow + wr * 64 + m * 16 + (lane >> 4) * 4 + j;
        const int col = bcol + wc * 64 + n * 16 + ar;
        const size_t idx = (size_t)row * ldo + col;
        const float v = acc[m][n][j] * scale;
        if constexpr (OUT == 0) {
          outf[idx] = v;
        } else if constexpr (OUT == 1) {
          f16 h, l;
          split_f32(v, h, l);
          oh[idx] = h;
          ol[idx] = l;
        } else {
          oh[idx] = (f16)v;
        }
      }
}

// ---- row softmax: S f32 [4096][4096] -> P f16 ----
__global__ __launch_bounds__(256) void k_softmax(const float* __restrict__ S,
                                                 f16* __restrict__ P) {
  const int row = blockIdx.x;
  const int tid = threadIdx.x;
  const int lane = tid & 63, wid = tid >> 6;
  const float* s = S + (size_t)row * 4096;
  float4 v[4];
#pragma unroll
  for (int i = 0; i < 4; ++i) v[i] = ((const float4*)s)[tid + 256 * i];

  float mx = -3.4e38f;
#pragma unroll
  for (int i = 0; i < 4; ++i)
    mx = fmaxf(mx, fmaxf(fmaxf(v[i].x, v[i].y), fmaxf(v[i].z, v[i].w)));
#pragma unroll
  for (int off = 1; off < 64; off <<= 1) mx = fmaxf(mx, __shfl_xor(mx, off, 64));
  __shared__ float red[4];
  if (lane == 0) red[wid] = mx;
  __syncthreads();
  mx = fmaxf(fmaxf(red[0], red[1]), fmaxf(red[2], red[3]));

  float sum = 0.f;
#pragma unroll
  for (int i = 0; i < 4; ++i) {
    v[i].x = __expf(v[i].x - mx); v[i].y = __expf(v[i].y - mx);
    v[i].z = __expf(v[i].z - mx); v[i].w = __expf(v[i].w - mx);
    sum += v[i].x + v[i].y + v[i].z + v[i].w;
  }
#pragma unroll
  for (int off = 1; off < 64; off <<= 1) sum += __shfl_xor(sum, off, 64);
  __syncthreads();
  if (lane == 0) red[wid] = sum;
  __syncthreads();
  sum = red[0] + red[1] + red[2] + red[3];
  const float inv = 1.0f / sum;

  f16* p = P + (size_t)row * 4096;
#pragma unroll
  for (int i = 0; i < 4; ++i) {
    f16x4v pv;
    pv[0] = (f16)(v[i].x * inv); pv[1] = (f16)(v[i].y * inv);
    pv[2] = (f16)(v[i].z * inv); pv[3] = (f16)(v[i].w * inv);
    ((f16x4v*)p)[tid + 256 * i] = pv;
  }
}

extern "C" void kernel_launch(void* const* d_in, const int* in_sizes, int n_in,
                              void* d_out, int out_size, void* d_ws,
                              size_t ws_size, hipStream_t stream) {
  const float* x = (const float*)d_in[0];
  const float* Wq = (const float*)d_in[1];
  const float* Wk = (const float*)d_in[2];
  const float* Wv = (const float*)d_in[3];
  float* out = (float*)d_out;
  char* ws = (char*)d_ws;
  const size_t MiB = 1u << 20;
  f16* xh = (f16*)(ws + 0 * MiB);
  f16* xl = (f16*)(ws + 8 * MiB);
  f16* Th = (f16*)(ws + 16 * MiB);
  f16* Tl = (f16*)(ws + 24 * MiB);
  f16* Vt = (f16*)(ws + 32 * MiB);
  float* S = (float*)(ws + 40 * MiB);  // 64 MiB
  f16* Pm = (f16*)(ws + 0 * MiB);      // reuses dead xh/xl/Th/Tl after S
  // temps living inside the (not-yet-written) S region:
  f16* Wqh = (f16*)(ws + 40 * MiB);
  f16* Wql = (f16*)(ws + 42 * MiB);
  f16* Wkh = (f16*)(ws + 44 * MiB);
  f16* Wkl = (f16*)(ws + 46 * MiB);
  f16* Mth = (f16*)(ws + 48 * MiB);
  f16* Mtl = (f16*)(ws + 50 * MiB);
  f16* Wtvh = (f16*)(ws + 52 * MiB);

  // allow 128 KiB dynamic LDS for the pipelined S kernel (idempotent)
  (void)hipFuncSetAttribute((const void*)k_qkt,
                            hipFuncAttributeMaxDynamicSharedMemorySize,
                            131072);

  // prep: split x, Wq, Wk (elementwise); transpose-split Wv (h only)
  k_split<<<dim3(1024, 1, 3), 256, 0, stream>>>(x, Wq, Wk, xh, xl, Wqh, Wql,
                                                Wkh, Wkl);
  k_wsplit_v<<<dim3(16, 16), 256, 0, stream>>>(Wv, Wtvh);
  // Mt[b][a] = (1/32) sum_q Wk[b,q] Wq[a,q]  (= M^T/32), split f16 out
  gemm_bt<3, 1><<<dim3(8, 8), 256, 65536, stream>>>(
      Wkh, Wkl, Wqh, Wql, 1024, nullptr, Mth, Mtl, 1024, 0.03125f);
  // T = x · (M/32): BT-GEMM(A=x, B=Mt), split f16 out
  gemm_bt<3, 1><<<dim3(32, 8), 256, 65536, stream>>>(
      xh, xl, Mth, Mtl, 1024, nullptr, Th, Tl, 1024, 1.0f);
  // Vt[d][i] = (x·Wv)^T: BT-GEMM(A=Wtvh, B=xh), single MFMA
  gemm_bt<1, 2><<<dim3(8, 32), 256, 32768, stream>>>(
      Wtvh, nullptr, xh, nullptr, 1024, nullptr, Vt, nullptr, 4096, 1.0f);
  // S = T · x^T  (scale already folded into Mt)
  k_qkt<<<dim3(256), 512, 131072, stream>>>(Th, Tl, xh, xl, S);
  k_softmax<<<dim3(4096), 256, 0, stream>>>(S, Pm);
  // out = P @ V = P · Vt^T
  gemm_bt<1, 0><<<dim3(32, 8), 256, 32768, stream>>>(
      Pm, nullptr, Vt, nullptr, 4096, out, nullptr, nullptr, 1024, 1.0f);
}